// Round 6
// baseline (241.070 us; speedup 1.0000x reference)
//
#include <hip/hip_runtime.h>
#include <math.h>

// minGRU: hg = x@Whg^T (bf16 MFMA, 256^2 pipelined) -> gates+scan (fp32)
//         -> out = h@Wout^T (bf16 MFMA, nt-coalesced f32 epilogue)
// x[4,4096,1024] f32, W_hg[2048,1024], W_out[1024,1024], out[4,4096,1024] f32

typedef unsigned short ushort_t;
typedef __attribute__((ext_vector_type(4))) float f32x4;
typedef __attribute__((ext_vector_type(8))) __bf16 bf16x8;
typedef __attribute__((ext_vector_type(8))) unsigned short u16x8;

constexpr int Bsz  = 4;
constexpr int S    = 4096;
constexpr int Din  = 1024;
constexpr int Dh   = 1024;
constexpr int M    = Bsz * S;      // 16384
constexpr int NCH  = 64;           // scan chunks along S
constexpr int CL   = S / NCH;      // 64

__device__ __forceinline__ unsigned short f2bf(float f) {
    unsigned int u = __float_as_uint(f);
    unsigned int r = (u + 0x7fffu + ((u >> 16) & 1u)) >> 16;   // RTN-even
    return (unsigned short)r;
}
__device__ __forceinline__ float bf2f(unsigned short u) {
    return __uint_as_float(((unsigned int)u) << 16);
}
__device__ __forceinline__ float sigf(float x) {
    x = fminf(fmaxf(x, -30.f), 30.f);
    return 1.0f / (1.0f + __expf(-x));
}
__device__ __forceinline__ void gld_lds16(const ushort_t* g, ushort_t* l) {
    __builtin_amdgcn_global_load_lds(
        (const __attribute__((address_space(1))) void*)g,
        (__attribute__((address_space(3))) void*)l, 16, 0, 0);
}

// one kernel converting all three f32 inputs to bf16
__global__ __launch_bounds__(256) void cvt_all(
    const float* __restrict__ x, const float* __restrict__ whg,
    const float* __restrict__ wout,
    ushort_t* __restrict__ xb, ushort_t* __restrict__ whgb,
    ushort_t* __restrict__ woutb)
{
    constexpr int NX = M * Din / 8;          // 2097152
    constexpr int NW = 2048 * 1024 / 8;      // 262144
    const int i = blockIdx.x * 256 + threadIdx.x;
    const float* src; ushort_t* dst; int k;
    if (i < NX)            { src = x;    dst = xb;    k = i; }
    else if (i < NX + NW)  { src = whg;  dst = whgb;  k = i - NX; }
    else                   { src = wout; dst = woutb; k = i - NX - NW; }
    const float4 a = ((const float4*)src)[(size_t)k * 2];
    const float4 b = ((const float4*)src)[(size_t)k * 2 + 1];
    u16x8 o;
    o[0] = f2bf(a.x); o[1] = f2bf(a.y); o[2] = f2bf(a.z); o[3] = f2bf(a.w);
    o[4] = f2bf(b.x); o[5] = f2bf(b.y); o[6] = f2bf(b.z); o[7] = f2bf(b.w);
    ((u16x8*)dst)[k] = o;
}

// C[M x N] = A[M x K] * B[N x K]^T, bf16 in, f32 accum.
// 256x256 tile, 8 waves (2Mx4N), K-tiles of 64, 4 phases/tile:
//   phase = {ds_read(p); stage 1 piece(T+1); vmcnt(N); barrier; lgkm(0); 16 MFMA}
// LDS: 2 bufs x (A 32KB + B 32KB) = 128 KiB.
// Pieces/tile (16KB each): A-mh0, Bk0, Bk1, A-mh1; staged in that order at
// q0..q3, consumed next tile. Per-wave FIFO invariants (verified):
//   entering any q0: outstanding = [Bk1(T), A-mh1(T)] = 4 loads;
//   q0: +A0' -> 6, vmcnt(4) drains Bk1(T)   (needed q1);
//   q1: +B0' -> 6, vmcnt(4) drains A-mh1(T) (needed q2);
//   q2: +B1' -> 6, no vmcnt;
//   q3: +A1' -> 8, vmcnt(4) drains A0',B0'  (needed next q0).
// Visibility: read(p)'s data drained by all waves at vmcnt(p-1) before
// barrier(p-1); read(p) issued after barrier(p-1). WAR: any piece's staging
// is >=3 phases after its region's last read (other buffer parity).
// Last tile peeled: no stages; vmcnt(2)@q0, vmcnt(0)@q1.
template<bool OUT_BF16>
__global__ __launch_bounds__(512, 2) void gemm256(
    const ushort_t* __restrict__ A, int lda,
    const ushort_t* __restrict__ B, int ldb,
    void* __restrict__ Cout, int ldc, int K, int nbx_log2)
{
    __shared__ ushort_t lds[2][2][16384];   // [buf][A/B][32KB]
    char* const ldsb = (char*)&lds[0][0][0];

    const int NT = K >> 6;                  // K-tiles (K=1024 -> 16)

    // XCD-bijective block swizzle (gridDim.x % 8 == 0)
    const int nwg = gridDim.x;
    const int cpx = nwg >> 3;
    const int bid = blockIdx.x;
    const int swz = (bid & 7) * cpx + (bid >> 3);
    const int bx  = swz & ((1 << nbx_log2) - 1);
    const int by  = swz >> nbx_log2;
    const int bm0 = by * 256;
    const int bn0 = bx * 256;

    const int t  = threadIdx.x;
    const int w  = t >> 6;           // wave 0..7
    const int l  = t & 63;
    const int wr = w >> 2;           // 0..1 -> 128 rows
    const int wc = w & 3;            // 0..3 -> 64 cols

    // ---- fragment read offsets (bytes) ----
    const int fr = l & 15;
    const int kg = l >> 4;
    const int a_row_byte = fr * 128;                       // + i*2048
    const int a_col0 = (kg * 16) ^ ((fr & 7) << 4);        // ks=0, swizzled
    const int a_col1 = a_col0 ^ 64;                        // ks=1
    const int b_row_byte = (wc * 64 + fr) * 64
                         + ((kg * 16) ^ (((fr >> 1) & 3) << 4));

    // ---- staging constants (pre-swizzled global source, linear LDS dest) ----
    const int rA      = w * 16 + (l >> 3);
    const int rowA0p  = ((rA     ) >> 6) * 128 + ((rA     ) & 63);
    const int rowA1p  = ((rA +  8) >> 6) * 128 + ((rA +  8) & 63);
    const int acolA   = (((l & 7) * 16) ^ (((l >> 3) & 7) << 4)) >> 1;  // elements
    const ushort_t* aS0 = A + (size_t)(bm0 + rowA0p) * lda + acolA;
    const ushort_t* aS1 = A + (size_t)(bm0 + rowA1p) * lda + acolA;
    const size_t aMh = (size_t)64 * lda;    // +64 source rows for mh=1
    const int brA  = w * 32 + (l >> 2);
    const int bcol = ((l & 3) ^ ((l >> 3) & 3)) * 8;       // elements
    const ushort_t* bS0 = B + (size_t)(bn0 + brA) * ldb + bcol;
    const ushort_t* bS1 = bS0 + (size_t)16 * ldb;

    auto stageA = [&](int Tt, int mh) {
        char* db = ldsb + (size_t)(Tt & 1) * 65536 + mh * 16384 + w * 2048;
        const size_t go = (size_t)mh * aMh + Tt * 64;
        gld_lds16(aS0 + go, (ushort_t*)db);
        gld_lds16(aS1 + go, (ushort_t*)(db + 1024));
    };
    auto stageB = [&](int Tt, int ks) {
        char* db = ldsb + (size_t)(Tt & 1) * 65536 + 32768 + ks * 16384 + w * 2048;
        const int go = Tt * 64 + ks * 32;
        gld_lds16(bS0 + go, (ushort_t*)db);
        gld_lds16(bS1 + go, (ushort_t*)(db + 1024));
    };

    f32x4 acc[8][4];
    #pragma unroll
    for (int i = 0; i < 8; ++i)
        #pragma unroll
        for (int j = 0; j < 4; ++j)
            acc[i][j] = (f32x4){0.f, 0.f, 0.f, 0.f};

    bf16x8 bfr0[4], bfr1[4];   // B frags ks0/ks1, persist across mh phases

    // ---- prologue: tile0 pieces in FIFO order [A0, B0, B1, A1] ----
    stageA(0, 0); stageB(0, 0); stageB(0, 1); stageA(0, 1);
    asm volatile("s_waitcnt vmcnt(4)" ::: "memory");   // A0,B0 landed
    __builtin_amdgcn_s_barrier();
    __builtin_amdgcn_sched_barrier(0);

    #define MFMA16(ACCB, AF, BF)                                          \
        asm volatile("s_waitcnt lgkmcnt(0)" ::: "memory");                \
        __builtin_amdgcn_sched_barrier(0);                                \
        __builtin_amdgcn_s_setprio(1);                                    \
        _Pragma("unroll")                                                 \
        for (int i = 0; i < 4; ++i)                                       \
            _Pragma("unroll")                                             \
            for (int j = 0; j < 4; ++j)                                   \
                acc[ACCB + i][j] = __builtin_amdgcn_mfma_f32_16x16x32_bf16( \
                    AF[i], BF[j], acc[ACCB + i][j], 0, 0, 0);             \
        __builtin_amdgcn_s_setprio(0);                                    \
        __builtin_amdgcn_sched_barrier(0);

    #pragma unroll 1
    for (int T = 0; T < NT - 1; ++T) {
        const char* abuf = ldsb + (size_t)(T & 1) * 65536;
        const char* bbuf = abuf + 32768;

        // ---- q0: reads A-mh0/ks0 + Bk0; stage A0(T+1); vmcnt(4) ----
        {
            #pragma unroll
            for (int j = 0; j < 4; ++j)
                bfr0[j] = *(const bf16x8*)(bbuf + j * 1024 + b_row_byte);
            bf16x8 af[4];
            #pragma unroll
            for (int i = 0; i < 4; ++i)
                af[i] = *(const bf16x8*)(abuf + wr * 8192 + i * 2048 + a_row_byte + a_col0);
            stageA(T + 1, 0);
            __builtin_amdgcn_sched_barrier(0);
            asm volatile("s_waitcnt vmcnt(4)" ::: "memory");
            __builtin_amdgcn_s_barrier();
            __builtin_amdgcn_sched_barrier(0);
            MFMA16(0, af, bfr0)
        }
        // ---- q1: reads A-mh0/ks1 + Bk1; stage B0(T+1); vmcnt(4) ----
        {
            #pragma unroll
            for (int j = 0; j < 4; ++j)
                bfr1[j] = *(const bf16x8*)(bbuf + 16384 + j * 1024 + b_row_byte);
            bf16x8 af[4];
            #pragma unroll
            for (int i = 0; i < 4; ++i)
                af[i] = *(const bf16x8*)(abuf + wr * 8192 + i * 2048 + a_row_byte + a_col1);
            stageB(T + 1, 0);
            __builtin_amdgcn_sched_barrier(0);
            asm volatile("s_waitcnt vmcnt(4)" ::: "memory");
            __builtin_amdgcn_s_barrier();
            __builtin_amdgcn_sched_barrier(0);
            MFMA16(0, af, bfr1)
        }
        // ---- q2: reads A-mh1/ks0; stage B1(T+1); no vmcnt ----
        {
            bf16x8 af[4];
            #pragma unroll
            for (int i = 0; i < 4; ++i)
                af[i] = *(const bf16x8*)(abuf + 16384 + wr * 8192 + i * 2048 + a_row_byte + a_col0);
            stageB(T + 1, 1);
            __builtin_amdgcn_sched_barrier(0);
            __builtin_amdgcn_s_barrier();
            __builtin_amdgcn_sched_barrier(0);
            MFMA16(4, af, bfr0)
        }
        // ---- q3: reads A-mh1/ks1; stage A1(T+1); vmcnt(4) ----
        {
            bf16x8 af[4];
            #pragma unroll
            for (int i = 0; i < 4; ++i)
                af[i] = *(const bf16x8*)(abuf + 16384 + wr * 8192 + i * 2048 + a_row_byte + a_col1);
            stageA(T + 1, 1);
            __builtin_amdgcn_sched_barrier(0);
            asm volatile("s_waitcnt vmcnt(4)" ::: "memory");
            __builtin_amdgcn_s_barrier();
            __builtin_amdgcn_sched_barrier(0);
            MFMA16(4, af, bfr1)
        }
    }

    // ---- peeled last tile: no stages; vmcnt(2)@q0, vmcnt(0)@q1 ----
    {
        const int T = NT - 1;
        const char* abuf = ldsb + (size_t)(T & 1) * 65536;
        const char* bbuf = abuf + 32768;
        {
            #pragma unroll
            for (int j = 0; j < 4; ++j)
                bfr0[j] = *(const bf16x8*)(bbuf + j * 1024 + b_row_byte);
            bf16x8 af[4];
            #pragma unroll
            for (int i = 0; i < 4; ++i)
                af[i] = *(const bf16x8*)(abuf + wr * 8192 + i * 2048 + a_row_byte + a_col0);
            __builtin_amdgcn_sched_barrier(0);
            asm volatile("s_waitcnt vmcnt(2)" ::: "memory");
            __builtin_amdgcn_s_barrier();
            __builtin_amdgcn_sched_barrier(0);
            MFMA16(0, af, bfr0)
        }
        {
            #pragma unroll
            for (int j = 0; j < 4; ++j)
                bfr1[j] = *(const bf16x8*)(bbuf + 16384 + j * 1024 + b_row_byte);
            bf16x8 af[4];
            #pragma unroll
            for (int i = 0; i < 4; ++i)
                af[i] = *(const bf16x8*)(abuf + wr * 8192 + i * 2048 + a_row_byte + a_col1);
            __builtin_amdgcn_sched_barrier(0);
            asm volatile("s_waitcnt vmcnt(0)" ::: "memory");
            __builtin_amdgcn_s_barrier();
            __builtin_amdgcn_sched_barrier(0);
            MFMA16(0, af, bfr1)
        }
        {
            bf16x8 af[4];
            #pragma unroll
            for (int i = 0; i < 4; ++i)
                af[i] = *(const bf16x8*)(abuf + 16384 + wr * 8192 + i * 2048 + a_row_byte + a_col0);
            __builtin_amdgcn_sched_barrier(0);
            __builtin_amdgcn_s_barrier();
            __builtin_amdgcn_sched_barrier(0);
            MFMA16(4, af, bfr0)
        }
        {
            bf16x8 af[4];
            #pragma unroll
            for (int i = 0; i < 4; ++i)
                af[i] = *(const bf16x8*)(abuf + 16384 + wr * 8192 + i * 2048 + a_row_byte + a_col1);
            __builtin_amdgcn_sched_barrier(0);
            __builtin_amdgcn_s_barrier();
            __builtin_amdgcn_sched_barrier(0);
            MFMA16(4, af, bfr1)
        }
    }
    #undef MFMA16

    // all waves' LDS reads complete before epilogue reuses LDS
    __builtin_amdgcn_s_barrier();

    if (OUT_BF16) {
        // scatter store: lanes 0-15 cover 32B bf16 chunks; acceptable for bf16
        #pragma unroll
        for (int i = 0; i < 8; ++i) {
            #pragma unroll
            for (int j = 0; j < 4; ++j) {
                const int col = bn0 + wc * 64 + j * 16 + fr;
                #pragma unroll
                for (int r = 0; r < 4; ++r) {
                    const int row = bm0 + wr * 128 + i * 16 + kg * 4 + r;
                    ((ushort_t*)Cout)[(size_t)row * ldc + col] = f2bf(acc[i][j][r]);
                }
            }
        }
    } else {
        // LDS-transposed, coalesced nontemporal float4 stores.
        // Per-wave region: 16 rows x 68 f32 (stride 272B, 16B-aligned, <=2-way banks)
        float* lw = (float*)(ldsb + w * 4352);
        #pragma unroll 1
        for (int i = 0; i < 8; ++i) {
            #pragma unroll
            for (int j = 0; j < 4; ++j)
                #pragma unroll
                for (int r = 0; r < 4; ++r)
                    lw[(kg * 4 + r) * 68 + j * 16 + fr] = acc[i][j][r];
            asm volatile("s_waitcnt lgkmcnt(0)" ::: "memory");
            __builtin_amdgcn_sched_barrier(0);
            #pragma unroll
            for (int ci = 0; ci < 4; ++ci) {
                const int rr = ci * 4 + kg;
                const f32x4 v = *(const f32x4*)&lw[rr * 68 + (l & 15) * 4];
                const int row = bm0 + wr * 128 + i * 16 + rr;
                const int col = bn0 + wc * 64 + (l & 15) * 4;
                __builtin_nontemporal_store(
                    v, (f32x4*)((float*)Cout + (size_t)row * ldc + col));
            }
            asm volatile("s_waitcnt lgkmcnt(0)" ::: "memory");
            __builtin_amdgcn_sched_barrier(0);
        }
    }
}

// ---- scan over S in 3 stages; gates recomputed from bf16 hg on the fly ----

__global__ __launch_bounds__(256) void scan_stage1(
    const ushort_t* __restrict__ hg, float* __restrict__ Abuf,
    float* __restrict__ hlbuf)
{
    const int g     = blockIdx.x * 256 + threadIdx.x;
    const int d     = g & (Dh - 1);
    const int chunk = (g >> 10) & (NCH - 1);
    const int b     = g >> 16;
    const size_t rowbase = (size_t)(b * S + chunk * CL) * 2048;
    float h = 0.0f, Aacc = 1.0f;
    #pragma unroll 4
    for (int i = 0; i < CL; ++i) {
        const float hid  = bf2f(hg[rowbase + (size_t)i * 2048 + d]);
        const float gate = bf2f(hg[rowbase + (size_t)i * 2048 + 1024 + d]);
        const float z  = sigf(gate);
        const float c  = sigf(-gate);
        const float gv = (hid >= 0.0f) ? (hid + 0.5f) : sigf(hid);
        h = fmaf(c, h, z * gv);
        Aacc *= c;
    }
    const size_t o = (size_t)(b * NCH + chunk) * Dh + d;
    Abuf[o]  = Aacc;
    hlbuf[o] = h;
}

__global__ __launch_bounds__(256) void scan_stage2(
    const float* __restrict__ Abuf, const float* __restrict__ hlbuf,
    float* __restrict__ Hs)
{
    const int g = blockIdx.x * 256 + threadIdx.x;   // 0..B*Dh-1
    const int d = g & (Dh - 1);
    const int b = g >> 10;
    float h = 0.0f;
    for (int ch = 0; ch < NCH; ++ch) {
        const size_t o = (size_t)(b * NCH + ch) * Dh + d;
        Hs[o] = h;
        h = fmaf(Abuf[o], h, hlbuf[o]);
    }
}

// replay chunk from Hs; write h (bf16) COMPACT into hout [M][1024]
__global__ __launch_bounds__(256) void scan_stage3(
    const ushort_t* __restrict__ hg, const float* __restrict__ Hs,
    ushort_t* __restrict__ hout)
{
    const int g     = blockIdx.x * 256 + threadIdx.x;
    const int d     = g & (Dh - 1);
    const int chunk = (g >> 10) & (NCH - 1);
    const int b     = g >> 16;
    const size_t rowbase = (size_t)(b * S + chunk * CL) * 2048;
    const size_t hbase   = (size_t)(b * S + chunk * CL) * 1024 + d;
    float h = Hs[(size_t)(b * NCH + chunk) * Dh + d];
    #pragma unroll 4
    for (int i = 0; i < CL; ++i) {
        const size_t ro = rowbase + (size_t)i * 2048;
        const float hid  = bf2f(hg[ro + d]);
        const float gate = bf2f(hg[ro + 1024 + d]);
        const float z  = sigf(gate);
        const float c  = sigf(-gate);
        const float gv = (hid >= 0.0f) ? (hid + 0.5f) : sigf(hid);
        h = fmaf(c, h, z * gv);
        hout[hbase + (size_t)i * 1024] = f2bf(h);
    }
}

extern "C" void kernel_launch(void* const* d_in, const int* in_sizes, int n_in,
                              void* d_out, int out_size, void* d_ws, size_t ws_size,
                              hipStream_t stream)
{
    (void)in_sizes; (void)n_in; (void)out_size; (void)ws_size;
    const float* x    = (const float*)d_in[0];
    const float* Whg  = (const float*)d_in[1];
    const float* Wout = (const float*)d_in[2];
    float* out = (float*)d_out;

    ushort_t* hgbuf = (ushort_t*)d_ws;                  // [M][2048] bf16  67.1 MB
    ushort_t* xb    = hgbuf + (size_t)M * 2048;         // [M][1024] bf16  33.5 MB (x, then h)
    ushort_t* whgb  = xb + (size_t)M * 1024;            // [2048][1024]     4.2 MB
    ushort_t* woutb = whgb + (size_t)2048 * 1024;       // [1024][1024]     2.1 MB
    float*    Abuf  = (float*)(woutb + (size_t)1024 * 1024);
    float*    hlbuf = Abuf + (size_t)Bsz * NCH * Dh;    // 1 MB each
    float*    Hsbuf = hlbuf + (size_t)Bsz * NCH * Dh;

    const dim3 blk(256);

    // fused conversion: (2097152 + 262144 + 131072)/256 = 9728 blocks
    cvt_all<<<dim3(9728), blk, 0, stream>>>(x, Whg, Wout, xb, whgb, woutb);

    // GEMM1: hg[M][2048] = x @ Whg^T  (bf16 out); grid 64x8 = 512
    gemm256<true><<<dim3(512), dim3(512), 0, stream>>>(
        xb, Din, whgb, Din, hgbuf, 2048, Din, 3);

    scan_stage1<<<dim3(Bsz * NCH * Dh / 256), blk, 0, stream>>>(hgbuf, Abuf, hlbuf);
    scan_stage2<<<dim3(Bsz * Dh / 256), blk, 0, stream>>>(Abuf, hlbuf, Hsbuf);
    scan_stage3<<<dim3(Bsz * NCH * Dh / 256), blk, 0, stream>>>(hgbuf, Hsbuf, xb);

    // GEMM2: out[M][1024] = h @ Wout^T  (f32 out); grid 64x4 = 256
    gemm256<false><<<dim3(256), dim3(512), 0, stream>>>(
        xb, Dh, woutb, Din, out, 1024, Dh, 2);
}